// Round 2
// baseline (362.136 us; speedup 1.0000x reference)
//
#include <hip/hip_runtime.h>
#include <stdint.h>

#define D 128

typedef unsigned int u32;
typedef unsigned short u16;
typedef __attribute__((ext_vector_type(8))) short short8;  // 8 bf16 bit-patterns (4 VGPRs)
typedef __attribute__((ext_vector_type(4))) float f32x4;

static __device__ __forceinline__ float bf2f(u16 h) {
    return __uint_as_float(((u32)h) << 16);
}
static __device__ __forceinline__ u16 f2bf(float f) {
    u32 u = __float_as_uint(f);
    u32 r = (u + 0x7fffu + ((u >> 16) & 1u)) >> 16;  // round-to-nearest-even
    return (u16)r;
}
static __device__ __forceinline__ int clampi(int v, int n) {
    if (v < 0) v = 0;
    if (v >= n) v = n - 1;
    return v;
}

// ---------------- init: zero hist/csr_pos + dtype probe (block 0, wave 0) ----------------
// flags[0]=1 item_emb/biases bf16 else fp32; flags[1]=1 edges int64 else int32;
// flags[2]=1 weights bf16 else fp32
__global__ void k_init(int* __restrict__ hist, int* __restrict__ csr_pos, int n,
                       const u16* __restrict__ emb_raw, const u32* __restrict__ ei_raw,
                       const u16* __restrict__ w_raw, int* __restrict__ flags) {
    int i = blockIdx.x * 256 + threadIdx.x;
    if (i < n) {
        hist[i] = 0;
        csr_pos[i] = 0;
    }
    if (blockIdx.x == 0 && threadIdx.x < 64) {
        int t = threadIdx.x;
        int se = 0, sw = 0, zz = 0;
#pragma unroll
        for (int q = 0; q < 4; q++) {
            int k = t * 4 + q;  // 256 samples
            u16 he = emb_raw[2 * k];
            u32 exe = (he >> 7) & 0xFF;
            if (he == 0 || (exe >= 0x60 && exe <= 0x8F)) se++;
            u16 hw = w_raw[2 * k];
            u32 exw = (hw >> 7) & 0xFF;
            if (hw == 0 || (exw >= 0x60 && exw <= 0x8F)) sw++;
            if (ei_raw[2 * k + 1] == 0) zz++;
        }
#pragma unroll
        for (int o = 32; o; o >>= 1) {
            se += __shfl_down(se, o);
            sw += __shfl_down(sw, o);
            zz += __shfl_down(zz, o);
        }
        if (t == 0) {
            flags[0] = (se >= 200) ? 1 : 0;
            flags[2] = (sw >= 200) ? 1 : 0;
            flags[1] = (zz >= 200) ? 1 : 0;
        }
    }
}

// ---------------- fused: degree histogram (blocks [0,eb)) + W-prep (blocks [eb,eb+192)) ----
// W -> MFMA B-fragment layout, split-bf16 (hi + lo residual).
// B-frag for mfma_f32_16x16x32_bf16: lane l holds W[k = ks*32 + (l>>4)*8 + e][j = c*16 + (l&15)],
// e = 0..7.  WB layout (u16): [layer][h(hi/lo)][c(8)][ks(4)][lane(64)][e(8)]  => 64 KB / layer.
__global__ void k_hw(const u32* __restrict__ ei, int E, int n,
                     const int* __restrict__ flags, int* __restrict__ hist,
                     const void* __restrict__ Wbase, u16* __restrict__ WB, int eb) {
    int bid = blockIdx.x;
    if (bid < eb) {
        int e = bid * 256 + threadIdx.x;
        if (e >= E) return;
        int d;
        if (flags[1]) d = ((const int2*)ei)[(size_t)E + e].x;  // int64: low word
        else          d = (int)ei[(size_t)E + e];
        atomicAdd(&hist[clampi(d, n)], 1);
    } else {
        int idx = (bid - eb) * 256 + threadIdx.x;  // [0, 3*16384)
        int e = idx & 7;
        int l = (idx >> 3) & 63;
        int ks = (idx >> 9) & 3;
        int c = (idx >> 11) & 7;
        int layer = idx >> 14;
        int k = ks * 32 + ((l >> 4) << 3) + e;
        int j = (c << 4) + (l & 15);
        size_t src = (size_t)layer * D * D + (size_t)k * D + j;
        float w = flags[2] ? bf2f(((const u16*)Wbase)[src]) : ((const float*)Wbase)[src];
        u16 hb = f2bf(w);
        u16 lb = f2bf(w - bf2f(hb));  // residual: Wh+Wl represents w to ~2^-17
        size_t o = (size_t)layer * 32768 + (size_t)((c * 4 + ks) * 64 + l) * 8 + e;
        WB[o] = hb;            // h=0 (hi)
        WB[o + 16384] = lb;    // h=1 (lo)
    }
}

// ---------------- scan1: per-block inclusive scan ----------------
__global__ void k_scan1(const int* __restrict__ hist, int n,
                        int* __restrict__ incl, int* __restrict__ bsums) {
    __shared__ int s[256];
    int t = threadIdx.x;
    int i = blockIdx.x * 256 + t;
    int v = (i < n) ? hist[i] : 0;
    s[t] = v;
    __syncthreads();
    for (int d2 = 1; d2 < 256; d2 <<= 1) {
        int add = (t >= d2) ? s[t - d2] : 0;
        __syncthreads();
        s[t] += add;
        __syncthreads();
    }
    if (i < n) incl[i] = s[t];
    if (t == 255) bsums[blockIdx.x] = s[255];
}

// ---------------- scan23: each block reduces its own bsums prefix, finalizes ----------------
__global__ void k_scan23(const int* __restrict__ hist, const int* __restrict__ bsums,
                         int n, int* __restrict__ csr_off, float* __restrict__ dinv) {
    __shared__ int s[256];
    int t = threadIdx.x, b = blockIdx.x;
    s[t] = (t < b) ? bsums[t] : 0;  // t<b<nb so in-bounds
    __syncthreads();
    for (int o = 128; o; o >>= 1) {
        if (t < o) s[t] += s[t + o];
        __syncthreads();
    }
    int add = s[0];
    int i = b * 256 + t;
    if (i < n) {
        int h = hist[i];
        csr_off[i] = add + csr_off[i] - h;  // incl -> excl + block offset
        dinv[i] = rsqrtf((float)(h + 1));   // +1 self-loop
    }
}

// ---------------- fused scatter (blocks [0,eb)) + x0 copy (blocks [eb,..)) ----------------
__global__ void k_sx(const u32* __restrict__ ei, int E, int n,
                     const int* __restrict__ flags,
                     const int* __restrict__ csr_off, int* __restrict__ csr_pos,
                     const float* __restrict__ dinv, int2* __restrict__ csr_pair,
                     const void* __restrict__ emb, int off_elems, int nD4,
                     float* __restrict__ out_x0, int eb) {
    int bid = blockIdx.x;
    if (bid < eb) {
        int e = bid * 256 + threadIdx.x;
        if (e >= E) return;
        int s, d;
        if (flags[1]) {
            s = ((const int2*)ei)[e].x;
            d = ((const int2*)ei)[(size_t)E + e].x;
        } else {
            s = (int)ei[e];
            d = (int)ei[(size_t)E + e];
        }
        s = clampi(s, n);
        d = clampi(d, n);
        int p = csr_off[d] + atomicAdd(&csr_pos[d], 1);
        if (p >= E) p = E - 1;
        csr_pair[p] = make_int2(s, __float_as_int(dinv[s] * dinv[d]));
    } else {
        int i = (bid - eb) * 256 + threadIdx.x;
        if (i >= nD4) return;
        float4 v;
        if (flags[0]) {
            ushort4 h = ((const ushort4*)((const u16*)emb + off_elems))[i];
            v = make_float4(bf2f(h.x), bf2f(h.y), bf2f(h.z), bf2f(h.w));
        } else {
            v = ((const float4*)((const float*)emb + off_elems))[i];
        }
        ((float4*)out_x0)[i] = v;
    }
}

// ---------------- GEMM: Y(bf16-packed) = A(fp32) @ W_l   via split-bf16 MFMA ----------------
// Block: 256 thr = 4 waves, 64 rows. Wave w: rows row0 = blk*64 + w*16, all 128 cols.
// No LDS: B-fragments read straight from WB (192 KB, L2-resident, coalesced 1 KB/wave/frag).
// mfma_f32_16x16x32_bf16 layouts (AMD convention, C/D HW-verified):
//   A[i][k]: lane = i + 16*(k/8), elem = k%8      (i = l&15 -> 32 B contiguous fp32 read)
//   B[k][j]: lane = j + 16*(k/8), elem = k%8      (pre-shuffled into WB by k_hw)
//   D[i][j]: lane = j + 16*(i/4), reg = i%4       (col = l&15, row = (l>>4)*4 + reg)
// Split: acc += Al*Bh + Ah*Bl + Ah*Bh  -> fp32-grade product precision, bf16-rounded output.
// Y pack per u32: (dim q, dim q+64) so both halves live in the SAME lane (c and c+4 frags).
__global__ __launch_bounds__(256) void k_gemm(const float* __restrict__ A,
                                              const u16* __restrict__ WB, int layer,
                                              int n, u32* __restrict__ Y) {
    int tid = threadIdx.x;
    int w = tid >> 6, l = tid & 63;
    int row0 = blockIdx.x * 64 + w * 16;
    int ar = row0 + (l & 15);
    if (ar >= n) ar = 0;  // OOB rows read row 0; masked at store
    const float* Ab = A + (size_t)ar * D + ((l >> 4) << 3);

    f32x4 acc[8] = {};
    const short8* bp = (const short8*)(WB + (size_t)layer * 32768);

#pragma unroll
    for (int ks = 0; ks < 4; ks++) {
        f32x4 a0 = *(const f32x4*)(Ab + ks * 32);
        f32x4 a1 = *(const f32x4*)(Ab + ks * 32 + 4);
        float av[8] = {a0.x, a0.y, a0.z, a0.w, a1.x, a1.y, a1.z, a1.w};
        short8 ah, al;
#pragma unroll
        for (int e = 0; e < 8; e++) {
            u16 h = f2bf(av[e]);
            ah[e] = (short)h;
            al[e] = (short)f2bf(av[e] - bf2f(h));
        }
#pragma unroll
        for (int c = 0; c < 8; c++) {
            short8 bh = bp[(c * 4 + ks) * 64 + l];
            short8 bl = bp[2048 + (c * 4 + ks) * 64 + l];
            acc[c] = __builtin_amdgcn_mfma_f32_16x16x32_bf16(al, bh, acc[c], 0, 0, 0);
            acc[c] = __builtin_amdgcn_mfma_f32_16x16x32_bf16(ah, bl, acc[c], 0, 0, 0);
            acc[c] = __builtin_amdgcn_mfma_f32_16x16x32_bf16(ah, bh, acc[c], 0, 0, 0);
        }
    }

    int rbase = row0 + ((l >> 4) << 2);
    int col = l & 15;
#pragma unroll
    for (int r = 0; r < 4; r++) {
        int gr = rbase + r;
        if (gr < n) {
#pragma unroll
            for (int c = 0; c < 4; c++) {
                u32 pack = (u32)f2bf(acc[c][r]) | ((u32)f2bf(acc[c + 4][r]) << 16);
                Y[(size_t)gr * 64 + c * 16 + col] = pack;
            }
        }
    }
}

// ---------------- aggregation: one WAVE per dst node, barrier-free ----------------
// 256-thr blocks = 4 independent waves. Lane t handles dims {t, t+64} (matches Y packing).
// Edge (src,norm) broadcast via v_readlane (SGPR, free) -> saddr gathers; 8 loads in
// flight, 4 acc pairs. No DS-pipe traffic in the hot loop.
__global__ __launch_bounds__(256) void k_agg(const u32* __restrict__ Y,
                                             const int* __restrict__ csr_off,
                                             const int* __restrict__ cnt,
                                             const int2* __restrict__ csr_pair,
                                             const float* __restrict__ dinv,
                                             const void* __restrict__ bias_base, int layer,
                                             const int* __restrict__ flags, int n, int nD,
                                             const float* __restrict__ out_base,
                                             float* __restrict__ out_x,
                                             float* __restrict__ out_tot) {
    int i = blockIdx.x * 4 + (threadIdx.x >> 6);
    if (i >= n) return;
    int t = threadIdx.x & 63;

    float di = dinv[i];
    float di2 = di * di;
    u32 yv = Y[(size_t)i * 64 + t];
    float a0 = bf2f((u16)(yv & 0xffffu)) * di2;  // self-loop, dim t
    float a1 = bf2f((u16)(yv >> 16)) * di2;      // dim t+64
    float b0 = 0.0f, b1 = 0.0f;
    float c0 = 0.0f, c1 = 0.0f;
    float d0 = 0.0f, d1 = 0.0f;

    int start = csr_off[i];
    int c = cnt[i];

    for (int base = 0; base < c; base += 64) {
        int m = c - base;
        if (m > 64) m = 64;
        int2 pr = (t < m) ? csr_pair[start + base + t] : make_int2(0, 0);
        int j = 0;
        for (; j + 7 < m; j += 8) {
            int s0 = __builtin_amdgcn_readlane(pr.x, j);
            int s1 = __builtin_amdgcn_readlane(pr.x, j + 1);
            int s2 = __builtin_amdgcn_readlane(pr.x, j + 2);
            int s3 = __builtin_amdgcn_readlane(pr.x, j + 3);
            int s4 = __builtin_amdgcn_readlane(pr.x, j + 4);
            int s5 = __builtin_amdgcn_readlane(pr.x, j + 5);
            int s6 = __builtin_amdgcn_readlane(pr.x, j + 6);
            int s7 = __builtin_amdgcn_readlane(pr.x, j + 7);
            float w0 = __uint_as_float((u32)__builtin_amdgcn_readlane(pr.y, j));
            float w1 = __uint_as_float((u32)__builtin_amdgcn_readlane(pr.y, j + 1));
            float w2 = __uint_as_float((u32)__builtin_amdgcn_readlane(pr.y, j + 2));
            float w3 = __uint_as_float((u32)__builtin_amdgcn_readlane(pr.y, j + 3));
            float w4 = __uint_as_float((u32)__builtin_amdgcn_readlane(pr.y, j + 4));
            float w5 = __uint_as_float((u32)__builtin_amdgcn_readlane(pr.y, j + 5));
            float w6 = __uint_as_float((u32)__builtin_amdgcn_readlane(pr.y, j + 6));
            float w7 = __uint_as_float((u32)__builtin_amdgcn_readlane(pr.y, j + 7));
            u32 v0 = Y[(size_t)s0 * 64 + t];
            u32 v1 = Y[(size_t)s1 * 64 + t];
            u32 v2 = Y[(size_t)s2 * 64 + t];
            u32 v3 = Y[(size_t)s3 * 64 + t];
            u32 v4 = Y[(size_t)s4 * 64 + t];
            u32 v5 = Y[(size_t)s5 * 64 + t];
            u32 v6 = Y[(size_t)s6 * 64 + t];
            u32 v7 = Y[(size_t)s7 * 64 + t];
            a0 += bf2f((u16)(v0 & 0xffffu)) * w0;
            a1 += bf2f((u16)(v0 >> 16)) * w0;
            b0 += bf2f((u16)(v1 & 0xffffu)) * w1;
            b1 += bf2f((u16)(v1 >> 16)) * w1;
            c0 += bf2f((u16)(v2 & 0xffffu)) * w2;
            c1 += bf2f((u16)(v2 >> 16)) * w2;
            d0 += bf2f((u16)(v3 & 0xffffu)) * w3;
            d1 += bf2f((u16)(v3 >> 16)) * w3;
            a0 += bf2f((u16)(v4 & 0xffffu)) * w4;
            a1 += bf2f((u16)(v4 >> 16)) * w4;
            b0 += bf2f((u16)(v5 & 0xffffu)) * w5;
            b1 += bf2f((u16)(v5 >> 16)) * w5;
            c0 += bf2f((u16)(v6 & 0xffffu)) * w6;
            c1 += bf2f((u16)(v6 >> 16)) * w6;
            d0 += bf2f((u16)(v7 & 0xffffu)) * w7;
            d1 += bf2f((u16)(v7 >> 16)) * w7;
        }
        for (; j < m; j++) {
            int s = __builtin_amdgcn_readlane(pr.x, j);
            float w = __uint_as_float((u32)__builtin_amdgcn_readlane(pr.y, j));
            u32 v = Y[(size_t)s * 64 + t];
            a0 += bf2f((u16)(v & 0xffffu)) * w;
            a1 += bf2f((u16)(v >> 16)) * w;
        }
    }
    float acc0 = (a0 + b0) + (c0 + d0);
    float acc1 = (a1 + b1) + (c1 + d1);

    float bb0, bb1;
    if (flags[0]) {
        const u16* bb = (const u16*)bias_base + layer * D;
        bb0 = bf2f(bb[t]);
        bb1 = bf2f(bb[t + 64]);
    } else {
        const float* bb = (const float*)bias_base + layer * D;
        bb0 = bb[t];
        bb1 = bb[t + 64];
    }
    float xv0 = acc0 + bb0, xv1 = acc1 + bb1;
    size_t base = (size_t)i * D + t;
    out_x[base] = xv0;
    out_x[base + 64] = xv1;

    if (out_tot) {  // layer 2: fuse total = x0+x1+x2+x3
        float s0 = out_base[(size_t)1 * nD + base] + out_base[(size_t)2 * nD + base] +
                   out_base[(size_t)3 * nD + base];
        float s1 = out_base[(size_t)1 * nD + base + 64] + out_base[(size_t)2 * nD + base + 64] +
                   out_base[(size_t)3 * nD + base + 64];
        out_tot[base] = s0 + xv0;
        out_tot[base + 64] = s1 + xv1;
    }
}

extern "C" void kernel_launch(void* const* d_in, const int* in_sizes, int n_in,
                              void* d_out, int out_size, void* d_ws, size_t ws_size,
                              hipStream_t stream) {
    float* out = (float*)d_out;              // fp32: [total, x0, x1, x2, x3]

    const int n = out_size / (5 * D);        // 50000

    // inputs identified by element count (robust to ordering)
    int i_emb = -1, i_ei = -1, i_w = -1, i_b = -1;
    {
        int order[8];
        int m = n_in > 8 ? 8 : n_in;
        for (int i = 0; i < m; i++) order[i] = i;
        for (int a = 0; a < m; a++)
            for (int b2 = a + 1; b2 < m; b2++)
                if (in_sizes[order[b2]] > in_sizes[order[a]]) {
                    int tmp = order[a]; order[a] = order[b2]; order[b2] = tmp;
                }
        i_emb = order[0];
        i_ei  = (m > 1) ? order[1] : 0;
        for (int i = 0; i < m; i++) {
            if (in_sizes[i] == 3 * D * D && i_w < 0) i_w = i;
            if (in_sizes[i] == 3 * D && i_b < 0) i_b = i;
        }
        if (i_w < 0) i_w = (m > 2) ? order[2] : 0;
        if (i_b < 0) i_b = (m > 3) ? order[3] : 0;
    }
    const void* emb  = d_in[i_emb];
    const void* wts  = d_in[i_w];
    const void* bias = d_in[i_b];
    const u32*  ei   = (const u32*)d_in[i_ei];

    const int E = in_sizes[i_ei] / 2;        // 600000
    const int rows = in_sizes[i_emb] / D;    // 80000
    const int off_elems = (rows - n) * D;

    char* p = (char*)d_ws;
    auto take = [&](size_t bytes) {
        char* r = p;
        p += (bytes + 255) & ~(size_t)255;
        return r;
    };
    int*   flags    = (int*)  take(3 * 4);
    int*   hist     = (int*)  take((size_t)n * 4);
    int*   csr_pos  = (int*)  take((size_t)n * 4);
    int*   csr_off  = (int*)  take((size_t)n * 4);
    int*   bsums    = (int*)  take(256 * 4);
    float* dinv     = (float*)take((size_t)n * 4);
    int2*  csr_pair = (int2*) take((size_t)E * 8);
    u32*   ybuf     = (u32*)  take((size_t)n * 64 * 4);   // bf16-packed Y
    u16*   wb       = (u16*)  take((size_t)3 * 32768 * 2); // W in MFMA B-frag layout (hi+lo)

    const int nD = n * D;
    const int nb = (n + 255) / 256;          // 196 (<=256 required by scan23)
    const int eb = (E + 255) / 256;
    const int x0b = (nD / 4 + 255) / 256;

    k_init<<<nb, 256, 0, stream>>>(hist, csr_pos, n, (const u16*)emb, ei,
                                   (const u16*)wts, flags);
    k_hw<<<eb + 192, 256, 0, stream>>>(ei, E, n, flags, hist, wts, wb, eb);
    k_scan1<<<nb, 256, 0, stream>>>(hist, n, csr_off, bsums);
    k_scan23<<<nb, 256, 0, stream>>>(hist, bsums, n, csr_off, dinv);
    k_sx<<<eb + x0b, 256, 0, stream>>>(ei, E, n, flags, csr_off, csr_pos, dinv,
                                       csr_pair, emb, off_elems, nD / 4,
                                       out + (size_t)nD, eb);

    const int ab = (n + 3) / 4;  // 4 nodes (waves) per 256-thr block
    for (int l = 0; l < 3; l++) {
        const float* A = out + (size_t)(1 + l) * nD;   // x_l slot (fp32)
        float* ox = out + (size_t)(2 + l) * nD;        // x_{l+1} slot
        k_gemm<<<(n + 63) / 64, 256, 0, stream>>>(A, wb, l, n, ybuf);
        k_agg<<<ab, 256, 0, stream>>>(ybuf, csr_off, hist, csr_pair, dinv, bias, l,
                                      flags, n, nD, out, ox,
                                      (l == 2) ? out : (float*)nullptr);
    }
}

// Round 3
// 350.216 us; speedup vs baseline: 1.0340x; 1.0340x over previous
//
#include <hip/hip_runtime.h>
#include <stdint.h>

#define D 128

typedef unsigned int u32;
typedef unsigned short u16;
typedef __attribute__((ext_vector_type(8))) short short8;  // 8 bf16 bit-patterns (4 VGPRs)
typedef __attribute__((ext_vector_type(4))) float f32x4;

static __device__ __forceinline__ float bf2f(u16 h) {
    return __uint_as_float(((u32)h) << 16);
}
static __device__ __forceinline__ u16 f2bf(float f) {
    u32 u = __float_as_uint(f);
    u32 r = (u + 0x7fffu + ((u >> 16) & 1u)) >> 16;  // round-to-nearest-even
    return (u16)r;
}
static __device__ __forceinline__ int clampi(int v, int n) {
    if (v < 0) v = 0;
    if (v >= n) v = n - 1;
    return v;
}

// ---------------- init: zero hist/csr_pos + dtype probe (block 0, wave 0) ----------------
// flags[0]=1 item_emb/biases bf16 else fp32; flags[1]=1 edges int64 else int32;
// flags[2]=1 weights bf16 else fp32
__global__ void k_init(int* __restrict__ hist, int* __restrict__ csr_pos, int n,
                       const u16* __restrict__ emb_raw, const u32* __restrict__ ei_raw,
                       const u16* __restrict__ w_raw, int* __restrict__ flags) {
    int i = blockIdx.x * 256 + threadIdx.x;
    if (i < n) {
        hist[i] = 0;
        csr_pos[i] = 0;
    }
    if (blockIdx.x == 0 && threadIdx.x < 64) {
        int t = threadIdx.x;
        int se = 0, sw = 0, zz = 0;
#pragma unroll
        for (int q = 0; q < 4; q++) {
            int k = t * 4 + q;  // 256 samples
            u16 he = emb_raw[2 * k];
            u32 exe = (he >> 7) & 0xFF;
            if (he == 0 || (exe >= 0x60 && exe <= 0x8F)) se++;
            u16 hw = w_raw[2 * k];
            u32 exw = (hw >> 7) & 0xFF;
            if (hw == 0 || (exw >= 0x60 && exw <= 0x8F)) sw++;
            if (ei_raw[2 * k + 1] == 0) zz++;
        }
#pragma unroll
        for (int o = 32; o; o >>= 1) {
            se += __shfl_down(se, o);
            sw += __shfl_down(sw, o);
            zz += __shfl_down(zz, o);
        }
        if (t == 0) {
            flags[0] = (se >= 200) ? 1 : 0;
            flags[2] = (sw >= 200) ? 1 : 0;
            flags[1] = (zz >= 200) ? 1 : 0;
        }
    }
}

// ---------------- fused: degree histogram (blocks [0,eb)) + W-prep (blocks [eb,eb+192)) ----
// W -> MFMA B-fragment layout, split-bf16 (hi + lo residual).
// B-frag for mfma_f32_16x16x32_bf16: lane l holds W[k = ks*32 + (l>>4)*8 + e][j = c*16 + (l&15)],
// e = 0..7.  WB layout (u16): [layer][h(hi/lo)][c(8)][ks(4)][lane(64)][e(8)]  => 64 KB / layer.
__global__ void k_hw(const u32* __restrict__ ei, int E, int n,
                     const int* __restrict__ flags, int* __restrict__ hist,
                     const void* __restrict__ Wbase, u16* __restrict__ WB, int eb) {
    int bid = blockIdx.x;
    if (bid < eb) {
        int e = bid * 256 + threadIdx.x;
        if (e >= E) return;
        int d;
        if (flags[1]) d = ((const int2*)ei)[(size_t)E + e].x;  // int64: low word
        else          d = (int)ei[(size_t)E + e];
        atomicAdd(&hist[clampi(d, n)], 1);
    } else {
        int idx = (bid - eb) * 256 + threadIdx.x;  // [0, 3*16384)
        int e = idx & 7;
        int l = (idx >> 3) & 63;
        int ks = (idx >> 9) & 3;
        int c = (idx >> 11) & 7;
        int layer = idx >> 14;
        int k = ks * 32 + ((l >> 4) << 3) + e;
        int j = (c << 4) + (l & 15);
        size_t src = (size_t)layer * D * D + (size_t)k * D + j;
        float w = flags[2] ? bf2f(((const u16*)Wbase)[src]) : ((const float*)Wbase)[src];
        u16 hb = f2bf(w);
        u16 lb = f2bf(w - bf2f(hb));  // residual: Wh+Wl represents w to ~2^-17
        size_t o = (size_t)layer * 32768 + (size_t)((c * 4 + ks) * 64 + l) * 8 + e;
        WB[o] = hb;            // h=0 (hi)
        WB[o + 16384] = lb;    // h=1 (lo)
    }
}

// ---------------- scan1: per-block inclusive scan ----------------
__global__ void k_scan1(const int* __restrict__ hist, int n,
                        int* __restrict__ incl, int* __restrict__ bsums) {
    __shared__ int s[256];
    int t = threadIdx.x;
    int i = blockIdx.x * 256 + t;
    int v = (i < n) ? hist[i] : 0;
    s[t] = v;
    __syncthreads();
    for (int d2 = 1; d2 < 256; d2 <<= 1) {
        int add = (t >= d2) ? s[t - d2] : 0;
        __syncthreads();
        s[t] += add;
        __syncthreads();
    }
    if (i < n) incl[i] = s[t];
    if (t == 255) bsums[blockIdx.x] = s[255];
}

// ---------------- scan23: each block reduces its own bsums prefix, finalizes ----------------
__global__ void k_scan23(const int* __restrict__ hist, const int* __restrict__ bsums,
                         int n, int* __restrict__ csr_off, float* __restrict__ dinv) {
    __shared__ int s[256];
    int t = threadIdx.x, b = blockIdx.x;
    s[t] = (t < b) ? bsums[t] : 0;  // t<b<nb so in-bounds
    __syncthreads();
    for (int o = 128; o; o >>= 1) {
        if (t < o) s[t] += s[t + o];
        __syncthreads();
    }
    int add = s[0];
    int i = b * 256 + t;
    if (i < n) {
        int h = hist[i];
        csr_off[i] = add + csr_off[i] - h;  // incl -> excl + block offset
        dinv[i] = rsqrtf((float)(h + 1));   // +1 self-loop
    }
}

// ---------------- fused scatter (blocks [0,eb)) + x0 copy (blocks [eb,..)) ----------------
__global__ void k_sx(const u32* __restrict__ ei, int E, int n,
                     const int* __restrict__ flags,
                     const int* __restrict__ csr_off, int* __restrict__ csr_pos,
                     const float* __restrict__ dinv, int2* __restrict__ csr_pair,
                     const void* __restrict__ emb, int off_elems, int nD4,
                     float* __restrict__ out_x0, int eb) {
    int bid = blockIdx.x;
    if (bid < eb) {
        int e = bid * 256 + threadIdx.x;
        if (e >= E) return;
        int s, d;
        if (flags[1]) {
            s = ((const int2*)ei)[e].x;
            d = ((const int2*)ei)[(size_t)E + e].x;
        } else {
            s = (int)ei[e];
            d = (int)ei[(size_t)E + e];
        }
        s = clampi(s, n);
        d = clampi(d, n);
        int p = csr_off[d] + atomicAdd(&csr_pos[d], 1);
        if (p >= E) p = E - 1;
        csr_pair[p] = make_int2(s, __float_as_int(dinv[s] * dinv[d]));
    } else {
        int i = (bid - eb) * 256 + threadIdx.x;
        if (i >= nD4) return;
        float4 v;
        if (flags[0]) {
            ushort4 h = ((const ushort4*)((const u16*)emb + off_elems))[i];
            v = make_float4(bf2f(h.x), bf2f(h.y), bf2f(h.z), bf2f(h.w));
        } else {
            v = ((const float4*)((const float*)emb + off_elems))[i];
        }
        ((float4*)out_x0)[i] = v;
    }
}

// ---------------- GEMM: Y(bf16-packed) = A(fp32) @ W_l   via split-bf16 MFMA ----------------
// Block: 256 thr = 4 waves, 64 rows. Wave w: rows row0 = blk*64 + w*16, all 128 cols.
// mfma_f32_16x16x32_bf16 layouts (AMD convention, C/D HW-verified):
//   A[i][k]: lane = i + 16*(k/8), elem = k%8      (i = l&15 -> 32 B contiguous fp32 read)
//   B[k][j]: lane = j + 16*(k/8), elem = k%8      (pre-shuffled into WB by k_hw)
//   D[i][j]: lane = j + 16*(i/4), reg = i%4       (col = l&15, row = (l>>4)*4 + reg)
// Split: acc += Al*Bh + Ah*Bl + Ah*Bh  -> fp32-grade product precision, bf16-rounded output.
// Y pack per u32: (dim q, dim q+64) so both halves live in the SAME lane (c and c+4 frags).
__global__ __launch_bounds__(256) void k_gemm(const float* __restrict__ A,
                                              const u16* __restrict__ WB, int layer,
                                              int n, u32* __restrict__ Y) {
    __shared__ f32x4 ldsv[4096];  // 64 KB: WB[layer] verbatim
    int tid = threadIdx.x;
    {
        const f32x4* src = (const f32x4*)(WB + (size_t)layer * 32768);
#pragma unroll
        for (int i = 0; i < 16; i++) ldsv[tid + 256 * i] = src[tid + 256 * i];
    }
    __syncthreads();

    int w = tid >> 6, l = tid & 63;
    int row0 = blockIdx.x * 64 + w * 16;
    int ar = row0 + (l & 15);
    if (ar >= n) ar = 0;  // OOB rows read row 0; masked at store
    const float* Ab = A + (size_t)ar * D + ((l >> 4) << 3);

    f32x4 acc[8] = {};
    const short8* bp = (const short8*)ldsv;

#pragma unroll
    for (int ks = 0; ks < 4; ks++) {
        f32x4 a0 = *(const f32x4*)(Ab + ks * 32);
        f32x4 a1 = *(const f32x4*)(Ab + ks * 32 + 4);
        float av[8] = {a0.x, a0.y, a0.z, a0.w, a1.x, a1.y, a1.z, a1.w};
        short8 ah, al;
#pragma unroll
        for (int e = 0; e < 8; e++) {
            u16 h = f2bf(av[e]);
            ah[e] = (short)h;
            al[e] = (short)f2bf(av[e] - bf2f(h));
        }
#pragma unroll
        for (int c = 0; c < 8; c++) {
            short8 bh = bp[(c * 4 + ks) * 64 + l];
            short8 bl = bp[2048 + (c * 4 + ks) * 64 + l];
            acc[c] = __builtin_amdgcn_mfma_f32_16x16x32_bf16(al, bh, acc[c], 0, 0, 0);
            acc[c] = __builtin_amdgcn_mfma_f32_16x16x32_bf16(ah, bl, acc[c], 0, 0, 0);
            acc[c] = __builtin_amdgcn_mfma_f32_16x16x32_bf16(ah, bh, acc[c], 0, 0, 0);
        }
    }

    int rbase = row0 + ((l >> 4) << 2);
    int col = l & 15;
#pragma unroll
    for (int r = 0; r < 4; r++) {
        int gr = rbase + r;
        if (gr < n) {
#pragma unroll
            for (int c = 0; c < 4; c++) {
                u32 pack = (u32)f2bf(acc[c][r]) | ((u32)f2bf(acc[c + 4][r]) << 16);
                Y[(size_t)gr * 64 + c * 16 + col] = pack;
            }
        }
    }
}

// ---------------- aggregation: one WAVE per dst node; 4 edges per gather instr ----------------
// 256-thr blocks = 4 independent waves. Wave split into 4 groups of 16 lanes (g = t>>4,
// p = t&15). Per 4-edge batch: group g handles edge j+g; lane (g,p) reads uint4 (u32s
// 4p..4p+3) of Y[src_g] -> ONE dwordx4 gathers 4 edges x 256 B. Broadcast of (src, w)
// via 2 ds_bpermute per batch. End: shfl_xor(16,32) group-reduce, coalesced float4 stores.
__global__ __launch_bounds__(256) void k_agg(const u32* __restrict__ Y,
                                             const int* __restrict__ csr_off,
                                             const int* __restrict__ cnt,
                                             const int2* __restrict__ csr_pair,
                                             const float* __restrict__ dinv,
                                             const void* __restrict__ bias_base, int layer,
                                             const int* __restrict__ flags, int n, int nD,
                                             const float* __restrict__ out_base,
                                             float* __restrict__ out_x,
                                             float* __restrict__ out_tot) {
    int i = blockIdx.x * 4 + (threadIdx.x >> 6);
    if (i >= n) return;
    int t = threadIdx.x & 63;
    int g = t >> 4, p = t & 15;

    float lo0 = 0.f, lo1 = 0.f, lo2 = 0.f, lo3 = 0.f;
    float hi0 = 0.f, hi1 = 0.f, hi2 = 0.f, hi3 = 0.f;

#define ACC4(V, W)                                                       \
    do {                                                                 \
        lo0 += __uint_as_float((V).x << 16) * (W);                       \
        hi0 += __uint_as_float((V).x & 0xffff0000u) * (W);               \
        lo1 += __uint_as_float((V).y << 16) * (W);                       \
        hi1 += __uint_as_float((V).y & 0xffff0000u) * (W);               \
        lo2 += __uint_as_float((V).z << 16) * (W);                       \
        hi2 += __uint_as_float((V).z & 0xffff0000u) * (W);               \
        lo3 += __uint_as_float((V).w << 16) * (W);                       \
        hi3 += __uint_as_float((V).w & 0xffff0000u) * (W);               \
    } while (0)

    // self-loop: all groups read the same row (L1 broadcast); only g==0 weights it
    float di = dinv[i];
    {
        uint4 vs = *(const uint4*)(Y + (size_t)i * 64 + p * 4);
        float ws = (g == 0) ? di * di : 0.0f;
        ACC4(vs, ws);
    }

    int start = csr_off[i];
    int c = cnt[i];

    for (int base = 0; base < c; base += 64) {
        int m = c - base;
        if (m > 64) m = 64;
        int2 pr = (t < m) ? csr_pair[start + base + t] : make_int2(0, 0);
        // 2-stage pipeline over 4-edge batches (padding lanes carry w=0, s=0)
        int s0 = __shfl(pr.x, g);
        float w0 = __uint_as_float((u32)__shfl(pr.y, g));
        uint4 v0 = *(const uint4*)(Y + (size_t)s0 * 64 + p * 4);
        for (int j = 4; j < m; j += 4) {
            int s1 = __shfl(pr.x, j + g);
            float w1 = __uint_as_float((u32)__shfl(pr.y, j + g));
            uint4 v1 = *(const uint4*)(Y + (size_t)s1 * 64 + p * 4);
            ACC4(v0, w0);
            v0 = v1;
            w0 = w1;
        }
        ACC4(v0, w0);
    }
#undef ACC4

    // group-reduce: lanes {p, p+16, p+32, p+48} hold the same dims
#pragma unroll
    for (int mask = 16; mask <= 32; mask <<= 1) {
        lo0 += __shfl_xor(lo0, mask);
        lo1 += __shfl_xor(lo1, mask);
        lo2 += __shfl_xor(lo2, mask);
        lo3 += __shfl_xor(lo3, mask);
        hi0 += __shfl_xor(hi0, mask);
        hi1 += __shfl_xor(hi1, mask);
        hi2 += __shfl_xor(hi2, mask);
        hi3 += __shfl_xor(hi3, mask);
    }

    if (g < 2) {  // g==0: dims 4p..4p+3 ; g==1: dims 64+4p..64+4p+3
        float r0 = g ? hi0 : lo0;
        float r1 = g ? hi1 : lo1;
        float r2 = g ? hi2 : lo2;
        float r3 = g ? hi3 : lo3;
        int off = g * 64 + 4 * p;
        float b0, b1, b2, b3;
        if (flags[0]) {
            const u16* bb = (const u16*)bias_base + layer * D + off;
            ushort4 h = *(const ushort4*)bb;
            b0 = bf2f(h.x); b1 = bf2f(h.y); b2 = bf2f(h.z); b3 = bf2f(h.w);
        } else {
            const float* bb = (const float*)bias_base + layer * D + off;
            float4 f = *(const float4*)bb;
            b0 = f.x; b1 = f.y; b2 = f.z; b3 = f.w;
        }
        float4 xv = make_float4(r0 + b0, r1 + b1, r2 + b2, r3 + b3);
        size_t base = (size_t)i * D + off;
        *(float4*)&out_x[base] = xv;

        if (out_tot) {  // layer 2: fuse total = x0+x1+x2+x3
            float4 s0 = *(const float4*)&out_base[(size_t)1 * nD + base];
            float4 s1 = *(const float4*)&out_base[(size_t)2 * nD + base];
            float4 s2 = *(const float4*)&out_base[(size_t)3 * nD + base];
            *(float4*)&out_tot[base] =
                make_float4(s0.x + s1.x + s2.x + xv.x, s0.y + s1.y + s2.y + xv.y,
                            s0.z + s1.z + s2.z + xv.z, s0.w + s1.w + s2.w + xv.w);
        }
    }
}

extern "C" void kernel_launch(void* const* d_in, const int* in_sizes, int n_in,
                              void* d_out, int out_size, void* d_ws, size_t ws_size,
                              hipStream_t stream) {
    float* out = (float*)d_out;              // fp32: [total, x0, x1, x2, x3]

    const int n = out_size / (5 * D);        // 50000

    // inputs identified by element count (robust to ordering)
    int i_emb = -1, i_ei = -1, i_w = -1, i_b = -1;
    {
        int order[8];
        int m = n_in > 8 ? 8 : n_in;
        for (int i = 0; i < m; i++) order[i] = i;
        for (int a = 0; a < m; a++)
            for (int b2 = a + 1; b2 < m; b2++)
                if (in_sizes[order[b2]] > in_sizes[order[a]]) {
                    int tmp = order[a]; order[a] = order[b2]; order[b2] = tmp;
                }
        i_emb = order[0];
        i_ei  = (m > 1) ? order[1] : 0;
        for (int i = 0; i < m; i++) {
            if (in_sizes[i] == 3 * D * D && i_w < 0) i_w = i;
            if (in_sizes[i] == 3 * D && i_b < 0) i_b = i;
        }
        if (i_w < 0) i_w = (m > 2) ? order[2] : 0;
        if (i_b < 0) i_b = (m > 3) ? order[3] : 0;
    }
    const void* emb  = d_in[i_emb];
    const void* wts  = d_in[i_w];
    const void* bias = d_in[i_b];
    const u32*  ei   = (const u32*)d_in[i_ei];

    const int E = in_sizes[i_ei] / 2;        // 600000
    const int rows = in_sizes[i_emb] / D;    // 80000
    const int off_elems = (rows - n) * D;

    char* p = (char*)d_ws;
    auto take = [&](size_t bytes) {
        char* r = p;
        p += (bytes + 255) & ~(size_t)255;
        return r;
    };
    int*   flags    = (int*)  take(3 * 4);
    int*   hist     = (int*)  take((size_t)n * 4);
    int*   csr_pos  = (int*)  take((size_t)n * 4);
    int*   csr_off  = (int*)  take((size_t)n * 4);
    int*   bsums    = (int*)  take(256 * 4);
    float* dinv     = (float*)take((size_t)n * 4);
    int2*  csr_pair = (int2*) take((size_t)E * 8);
    u32*   ybuf     = (u32*)  take((size_t)n * 64 * 4);   // bf16-packed Y
    u16*   wb       = (u16*)  take((size_t)3 * 32768 * 2); // W in MFMA B-frag layout (hi+lo)

    const int nD = n * D;
    const int nb = (n + 255) / 256;          // 196 (<=256 required by scan23)
    const int eb = (E + 255) / 256;
    const int x0b = (nD / 4 + 255) / 256;

    k_init<<<nb, 256, 0, stream>>>(hist, csr_pos, n, (const u16*)emb, ei,
                                   (const u16*)wts, flags);
    k_hw<<<eb + 192, 256, 0, stream>>>(ei, E, n, flags, hist, wts, wb, eb);
    k_scan1<<<nb, 256, 0, stream>>>(hist, n, csr_off, bsums);
    k_scan23<<<nb, 256, 0, stream>>>(hist, bsums, n, csr_off, dinv);
    k_sx<<<eb + x0b, 256, 0, stream>>>(ei, E, n, flags, csr_off, csr_pos, dinv,
                                       csr_pair, emb, off_elems, nD / 4,
                                       out + (size_t)nD, eb);

    const int ab = (n + 3) / 4;  // 4 nodes (waves) per 256-thr block
    for (int l = 0; l < 3; l++) {
        const float* A = out + (size_t)(1 + l) * nD;   // x_l slot (fp32)
        float* ox = out + (size_t)(2 + l) * nD;        // x_{l+1} slot
        k_gemm<<<(n + 63) / 64, 256, 0, stream>>>(A, wb, l, n, ybuf);
        k_agg<<<ab, 256, 0, stream>>>(ybuf, csr_off, hist, csr_pair, dinv, bias, l,
                                      flags, n, nD, out, ox,
                                      (l == 2) ? out : (float*)nullptr);
    }
}